// Round 9
// baseline (271.222 us; speedup 1.0000x reference)
//
#include <hip/hip_runtime.h>
#include <hip/hip_bf16.h>
#include <float.h>

// Problem constants
constexpr int B  = 64;
constexpr int C  = 256;
constexpr int HW = 1024;   // 32*32
constexpr int K  = 1024;
constexpr float BETA = 0.25f;
constexpr float NTOT_INV = 1.0f / 16777216.0f;  // 1 / (64*256*32*32)

typedef __attribute__((ext_vector_type(8))) short bf16x8;
typedef __attribute__((ext_vector_type(4))) float floatx4;

union U16 { uint4 u; bf16x8 b; };

__device__ inline unsigned short f2bf(float x) {
    unsigned u = __float_as_uint(x);
    return (unsigned short)((u + 0x7FFFu + ((u >> 16) & 1u)) >> 16);  // RNE
}

// --- kernel 1: emb fp32 -> bf16 TILED [ks][code][32ch] + esq1 + esum ---
// esq1[k] = 1 + ||e_k||^2 (fp32); esum[k] = sum_c e_k[c] (commitment loss).
// grid 256 x 256 threads. Also zeroes loss accumulators.
__global__ __launch_bounds__(256) void prep_kernel(const float* __restrict__ emb,
                                                   short* __restrict__ ebf2,
                                                   float* __restrict__ esq1,
                                                   float* __restrict__ esum,
                                                   float* __restrict__ acc_loss) {
    if (blockIdx.x == 0 && threadIdx.x < 2) acc_loss[threadIdx.x] = 0.0f;
    const int wid  = threadIdx.x >> 6;
    const int lane = threadIdx.x & 63;
    const int k    = blockIdx.x * 4 + wid;
    const float4 v = *(const float4*)(emb + (size_t)k * C + lane * 4);
    ushort4 pk = { f2bf(v.x), f2bf(v.y), f2bf(v.z), f2bf(v.w) };
    *(ushort4*)&ebf2[((size_t)(lane >> 3) * K + k) * 32 + (lane & 7) * 4] = pk;
    float s  = v.x * v.x + v.y * v.y + v.z * v.z + v.w * v.w;
    float s2 = v.x + v.y + v.z + v.w;
#pragma unroll
    for (int off = 32; off > 0; off >>= 1) {
        s  += __shfl_down(s,  off, 64);
        s2 += __shfl_down(s2, off, 64);
    }
    if (lane == 0) { esq1[k] = 1.0f + s; esum[k] = s2; }
}

// --- kernel 2: z NCHW f32 -> zt2 slabs (exact vq_dist LDS layout) + zsq + sum(z).
// zt2 slab per 64-token block TB: [kq=32][tokL=64][8ch] bf16 = 32KB.
// All global reads/writes are 1KB-contiguous wave bursts. zsq computed in fp32
// BEFORE bf16 rounding. grid 256 blocks (b, hw-quarter) x 512 threads.
__global__ __launch_bounds__(512) void zt_kernel(const float* __restrict__ z,
                                                 short* __restrict__ zt2,
                                                 float* __restrict__ zsq,
                                                 float* __restrict__ acc_loss) {
    __shared__ unsigned int U[256 * 33];   // 33 KB (+1 pad col: conflict-free reads)
    __shared__ float zsqP[8][256];         // 8 KB per-wave zsq partials
    __shared__ float zsums[8];
    const int tid = threadIdx.x;           // 0..511
    const int wv  = tid >> 6;              // wave 0..7
    const int L   = tid & 63;
    const int b   = blockIdx.x >> 2;
    const int quarter = blockIdx.x & 3;
    const int hw0 = quarter * 256;
    const float* zb = z + (size_t)b * C * HW;
    const int TB0 = b * 16 + quarter * 4;  // first of 4 token-blocks

    float zq4[4] = {0.f, 0.f, 0.f, 0.f};
    float zs = 0.f;

    for (int ch0 = 0; ch0 < C; ch0 += 64) {
        // stage-in: wave wv reads channels ch0+wv*8 .. +7, each one 1KB burst
        float4 va[8];
#pragma unroll
        for (int i = 0; i < 8; ++i) {
            const int c = ch0 + wv * 8 + i;
            va[i] = *(const float4*)(zb + (size_t)c * HW + hw0 + L * 4);
        }
        // fp32 loss partials (pre-rounding): tokens 4L..4L+3
#pragma unroll
        for (int i = 0; i < 8; ++i) {
            const float* p = (const float*)&va[i];
#pragma unroll
            for (int j = 0; j < 4; ++j) { zq4[j] = fmaf(p[j], p[j], zq4[j]); zs += p[j]; }
        }
#pragma unroll
        for (int i = 0; i < 8; i += 2) {
            const int cu = (wv * 8 + i) >> 1;          // channel-pair column
            const float* p0 = (const float*)&va[i];
            const float* p1 = (const float*)&va[i + 1];
#pragma unroll
            for (int j = 0; j < 4; ++j) {
                unsigned int u = ((unsigned int)f2bf(p0[j])) |
                                 ((unsigned int)f2bf(p1[j]) << 16);
                U[(L * 4 + j) * 33 + cu] = u;
            }
        }
        __syncthreads();
        // stage-out: slot -> (t4, ksl, q, tokL); consecutive tid -> consecutive
        // 16B granules of one (TB, kq) row => 1KB contiguous per wave.
#pragma unroll
        for (int r = 0; r < 4; ++r) {
            const int slot = r * 512 + tid;
            const int t4   = slot >> 9;
            const int ksl  = (slot >> 8) & 1;
            const int qq   = (slot >> 6) & 3;
            const int tokL = slot & 63;
            const int tokl = t4 * 64 + tokL;
            const int cb   = ksl * 16 + qq * 4;
            uint4 w;
            w.x = U[tokl * 33 + cb + 0];
            w.y = U[tokl * 33 + cb + 1];
            w.z = U[tokl * 33 + cb + 2];
            w.w = U[tokl * 33 + cb + 3];
            const int kq = ((ch0 >> 5) + ksl) * 4 + qq;
            *(uint4*)&zt2[(size_t)(TB0 + t4) * 16384 + kq * 512 + tokL * 8] = w;
        }
        __syncthreads();
    }

    // zsq: combine the 8 waves' channel-partials per token
#pragma unroll
    for (int j = 0; j < 4; ++j) zsqP[wv][L * 4 + j] = zq4[j];
#pragma unroll
    for (int off = 32; off > 0; off >>= 1) zs += __shfl_down(zs, off, 64);
    if (L == 0) zsums[wv] = zs;
    __syncthreads();
    if (tid < 256) {
        float s = 0.f;
#pragma unroll
        for (int w = 0; w < 8; ++w) s += zsqP[w][tid];
        zsq[(size_t)b * HW + hw0 + tid] = s;
    }
    if (tid == 0) {
        float t = 0.f;
#pragma unroll
        for (int w = 0; w < 8; ++w) t += zsums[w];
        atomicAdd(&acc_loss[1], -t);   // s_d = sum(esum[km]) - sum(z)
    }
}

// --- kernel 3: distances + argmin + loss. 4 waves/block, 64 tokens/block,
// wave w handles codes [w*256, +256) in 8 chunks of 32 codes (acc[2][4] tile:
// 32 AGPR + ~70 VGPR -> fits the (256,4) 128-reg cap WITHOUT spilling, unlike
// the acc[4][4] ~190-reg body which spilled at every cap <256: R1/R5/R7/R8).
// 4 blocks/CU = 16 waves/CU, grid 1024 = exactly one round.
// Spill signature to watch: VGPR<90 or WRITE_SIZE >> 1MB -> revert to R6.
// grid 1024 x 256.
__global__ __launch_bounds__(256, 4) void vq_dist(const short* __restrict__ zt2,
                                                  const short* __restrict__ ebf2,
                                                  const float* __restrict__ esq1,
                                                  const float* __restrict__ esum,
                                                  const float* __restrict__ zsq,
                                                  unsigned short* __restrict__ inds,
                                                  float* __restrict__ acc_loss) {
    __shared__ short Zs[32 * 512];          // 32 KB, layout [kq][tokL][8ch]
    __shared__ unsigned int warr[4 * 64];

    const int tid = threadIdx.x;
    const int wid = tid >> 6;
    const int L   = tid & 63;
    const int q   = L >> 4;
    const int l15 = L & 15;
    const int TB  = blockIdx.x;
    const int tok0 = TB * 64;

    // ---- phase 1: coalesced slab copy (8 x uint4 per thread) ----
    const short* src = zt2 + (size_t)TB * 16384;
#pragma unroll
    for (int i = 0; i < 8; ++i) {
        const int g = i * 256 + tid;
        *(uint4*)&Zs[g * 8] = *(const uint4*)&src[g * 8];
    }
    __syncthreads();

    // ---- phase 2: K loop, 8 chunks x 32 codes ----
    unsigned int best[4] = {0xFFFFFFFFu, 0xFFFFFFFFu, 0xFFFFFFFFu, 0xFFFFFFFFu};

    for (int kk = 0; kk < 8; ++kk) {
        const int k0 = wid * 256 + kk * 32;
        floatx4 acc[2][4];   // [m code tile][t token tile]
#pragma unroll
        for (int m = 0; m < 2; ++m)
#pragma unroll
            for (int t = 0; t < 4; ++t) acc[m][t] = (floatx4){0.f, 0.f, 0.f, 0.f};

#pragma unroll
        for (int ks = 0; ks < 8; ++ks) {
            U16 a[2];
#pragma unroll
            for (int m = 0; m < 2; ++m)
                a[m].u = *(const uint4*)(ebf2 + ((size_t)ks * K + (k0 + m * 16 + l15)) * 32 + q * 8);
            bf16x8 zf[4];
#pragma unroll
            for (int t = 0; t < 4; ++t)
                zf[t] = *(const bf16x8*)&Zs[(ks * 4 + q) * 512 + (t * 16 + l15) * 8];
#pragma unroll
            for (int m = 0; m < 2; ++m)
#pragma unroll
                for (int t = 0; t < 4; ++t)
                    acc[m][t] = __builtin_amdgcn_mfma_f32_16x16x32_bf16(a[m].b, zf[t], acc[m][t], 0, 0, 0);
        }

        // d = 1 + ||e||^2 - 2 z.e  (positive => bit-monotone); low 10 bits = code
#pragma unroll
        for (int m = 0; m < 2; ++m) {
            const float4 eq = *(const float4*)&esq1[k0 + m * 16 + q * 4];
            const float eqa[4] = {eq.x, eq.y, eq.z, eq.w};
#pragma unroll
            for (int r = 0; r < 4; ++r) {
                const unsigned int code = (unsigned int)(k0 + m * 16 + q * 4 + r);
#pragma unroll
                for (int t = 0; t < 4; ++t) {
                    float d = fmaf(-2.0f, acc[m][t][r], eqa[r]);
                    unsigned int u = (__float_as_uint(d) & 0xFFFFFC00u) | code;
                    best[t] = best[t] < u ? best[t] : u;
                }
            }
        }
    }

    // ---- phase 3: argmin reduce; epilogue computes loss terms from d_min ----
#pragma unroll
    for (int t = 0; t < 4; ++t) {
        unsigned int o = (unsigned int)__shfl_xor((int)best[t], 16, 64);
        best[t] = best[t] < o ? best[t] : o;
        o = (unsigned int)__shfl_xor((int)best[t], 32, 64);
        best[t] = best[t] < o ? best[t] : o;
    }
    warr[wid * 64 + L] = (q == 0) ? best[0] : (q == 1) ? best[1] : (q == 2) ? best[2] : best[3];
    __syncthreads();

    if (tid < 64) {
        unsigned int u0 = warr[tid];
        unsigned int u1 = warr[64 + tid];
        unsigned int u2 = warr[128 + tid];
        unsigned int u3 = warr[192 + tid];
        u0 = u0 < u1 ? u0 : u1;
        u2 = u2 < u3 ? u2 : u3;
        u0 = u0 < u2 ? u0 : u2;
        const int km = (int)(u0 & 1023u);
        inds[tok0 + tid] = (unsigned short)km;
        // ||e_km - z||^2 = (d_min - 1) + ||z||^2   (zsq is fp32, pre-rounding)
        const float d = __uint_as_float(u0 & 0xFFFFFC00u);
        float ssq = d - 1.0f + zsq[tok0 + tid];
        float sd  = esum[km];
#pragma unroll
        for (int off = 32; off > 0; off >>= 1) {
            ssq += __shfl_down(ssq, off, 64);
            sd  += __shfl_down(sd,  off, 64);
        }
        if (tid == 0) {
            atomicAdd(&acc_loss[0], ssq);
            atomicAdd(&acc_loss[1], sd);
        }
    }
}

// --- kernel 4: pure gather-write: out[b][c][hw] = emb[km(b,hw)][c].
// (straight-through forward == z_q exactly; no z traffic, no loss here).
// grid 2048 (b x ch-octet) x 256 threads; out writes are 1KB wave bursts;
// gathers are 2 x float4 per km from the L2-resident 1MB codebook.
__global__ __launch_bounds__(256) void vq_write(const float* __restrict__ emb,
                                                const unsigned short* __restrict__ inds,
                                                float* __restrict__ out) {
    const int tid = threadIdx.x;
    const int wv  = tid >> 6;
    const int L   = tid & 63;
    const int b   = blockIdx.x >> 5;
    const int c0  = (blockIdx.x & 31) * 8;
    const int hw  = wv * 256 + L * 4;

    ushort4 kmv = *(const ushort4*)(inds + b * HW + hw);
    const unsigned short kma[4] = {kmv.x, kmv.y, kmv.z, kmv.w};
    float4 elo[4], ehi[4];
#pragma unroll
    for (int j = 0; j < 4; ++j) {
        const float* er = emb + (size_t)kma[j] * C + c0;
        elo[j] = *(const float4*)er;
        ehi[j] = *(const float4*)(er + 4);
    }
    float* ob = out + ((size_t)b * C + c0) * HW + hw;
#pragma unroll
    for (int cc = 0; cc < 4; ++cc) {
        float4 v = { ((const float*)&elo[0])[cc], ((const float*)&elo[1])[cc],
                     ((const float*)&elo[2])[cc], ((const float*)&elo[3])[cc] };
        *(float4*)(ob + (size_t)cc * HW) = v;
    }
#pragma unroll
    for (int cc = 0; cc < 4; ++cc) {
        float4 v = { ((const float*)&ehi[0])[cc], ((const float*)&ehi[1])[cc],
                     ((const float*)&ehi[2])[cc], ((const float*)&ehi[3])[cc] };
        *(float4*)(ob + (size_t)(4 + cc) * HW) = v;
    }
}

// --- kernel 5: finalize scalar loss ---
__global__ void loss_kernel(const float* __restrict__ acc_loss,
                            float* __restrict__ out_loss) {
    out_loss[0] = acc_loss[0] * NTOT_INV + BETA * (acc_loss[1] * NTOT_INV);
}

extern "C" void kernel_launch(void* const* d_in, const int* in_sizes, int n_in,
                              void* d_out, int out_size, void* d_ws, size_t ws_size,
                              hipStream_t stream) {
    const float* z   = (const float*)d_in[0];   // [64,256,32,32]
    const float* emb = (const float*)d_in[1];   // [1024,256]
    float* out = (float*)d_out;                 // [16777216 z_q] + [1 loss]
    float* ws  = (float*)d_ws;
    float* acc  = ws;                               // 2 floats
    float* esq1 = ws + 64;                          // 1024 floats
    float* esum = ws + 64 + 1024;                   // 1024 floats
    short* ebf2 = (short*)(ws + 64 + 2048);         // 512 KB (tiled codebook)
    unsigned short* inds = (unsigned short*)(ebf2 + (size_t)K * C);  // 128 KB
    // Scratch in the out buffer (consumed by vq_dist before vq_write overwrites):
    short* zt2 = (short*)out;                       // 33.5 MB (slab-layout z)
    float* zsq = out + (size_t)12 * 1024 * 1024;    // 256 KB at 48MB offset

    prep_kernel<<<dim3(K / 4), 256, 0, stream>>>(emb, ebf2, esq1, esum, acc);
    zt_kernel<<<dim3(256), 512, 0, stream>>>(z, zt2, zsq, acc);
    vq_dist<<<dim3(1024), 256, 0, stream>>>(zt2, ebf2, esq1, esum, zsq, inds, acc);
    vq_write<<<dim3(2048), 256, 0, stream>>>(emb, inds, out);
    loss_kernel<<<1, 1, 0, stream>>>(acc, out + (size_t)B * C * HW);
}

// Round 10
// 194.332 us; speedup vs baseline: 1.3957x; 1.3957x over previous
//
#include <hip/hip_runtime.h>
#include <hip/hip_bf16.h>
#include <float.h>

// Problem constants
constexpr int B  = 64;
constexpr int C  = 256;
constexpr int HW = 1024;   // 32*32
constexpr int K  = 1024;
constexpr float BETA = 0.25f;
constexpr float NTOT_INV = 1.0f / 16777216.0f;  // 1 / (64*256*32*32)

typedef __attribute__((ext_vector_type(8))) short bf16x8;
typedef __attribute__((ext_vector_type(4))) float floatx4;

union U16 { uint4 u; bf16x8 b; };

__device__ inline unsigned short f2bf(float x) {
    unsigned u = __float_as_uint(x);
    return (unsigned short)((u + 0x7FFFu + ((u >> 16) & 1u)) >> 16);  // RNE
}

// --- kernel 1: emb fp32 -> bf16 TILED [ks][code][32ch] + esq1 + esum ---
// esq1[k] = 1 + ||e_k||^2 (fp32); esum[k] = sum_c e_k[c] (commitment loss).
// grid 256 x 256 threads. Also zeroes loss accumulators.
__global__ __launch_bounds__(256) void prep_kernel(const float* __restrict__ emb,
                                                   short* __restrict__ ebf2,
                                                   float* __restrict__ esq1,
                                                   float* __restrict__ esum,
                                                   float* __restrict__ acc_loss) {
    if (blockIdx.x == 0 && threadIdx.x < 2) acc_loss[threadIdx.x] = 0.0f;
    const int wid  = threadIdx.x >> 6;
    const int lane = threadIdx.x & 63;
    const int k    = blockIdx.x * 4 + wid;
    const float4 v = *(const float4*)(emb + (size_t)k * C + lane * 4);
    ushort4 pk = { f2bf(v.x), f2bf(v.y), f2bf(v.z), f2bf(v.w) };
    *(ushort4*)&ebf2[((size_t)(lane >> 3) * K + k) * 32 + (lane & 7) * 4] = pk;
    float s  = v.x * v.x + v.y * v.y + v.z * v.z + v.w * v.w;
    float s2 = v.x + v.y + v.z + v.w;
#pragma unroll
    for (int off = 32; off > 0; off >>= 1) {
        s  += __shfl_down(s,  off, 64);
        s2 += __shfl_down(s2, off, 64);
    }
    if (lane == 0) { esq1[k] = 1.0f + s; esum[k] = s2; }
}

// --- kernel 2: z NCHW f32 -> zt2 slabs (exact vq_dist LDS layout) + zsq + sum(z).
// zt2 slab per 64-token block TB: [kq=32][tokL=64][8ch] bf16 = 32KB.
// All global reads/writes are 1KB-contiguous wave bursts. zsq computed in fp32
// BEFORE bf16 rounding. grid 256 blocks (b, hw-quarter) x 512 threads.
__global__ __launch_bounds__(512) void zt_kernel(const float* __restrict__ z,
                                                 short* __restrict__ zt2,
                                                 float* __restrict__ zsq,
                                                 float* __restrict__ acc_loss) {
    __shared__ unsigned int U[256 * 33];   // 33 KB (+1 pad col: conflict-free reads)
    __shared__ float zsqP[8][256];         // 8 KB per-wave zsq partials
    __shared__ float zsums[8];
    const int tid = threadIdx.x;           // 0..511
    const int wv  = tid >> 6;              // wave 0..7
    const int L   = tid & 63;
    const int b   = blockIdx.x >> 2;
    const int quarter = blockIdx.x & 3;
    const int hw0 = quarter * 256;
    const float* zb = z + (size_t)b * C * HW;
    const int TB0 = b * 16 + quarter * 4;  // first of 4 token-blocks

    float zq4[4] = {0.f, 0.f, 0.f, 0.f};
    float zs = 0.f;

    for (int ch0 = 0; ch0 < C; ch0 += 64) {
        // stage-in: wave wv reads channels ch0+wv*8 .. +7, each one 1KB burst
        float4 va[8];
#pragma unroll
        for (int i = 0; i < 8; ++i) {
            const int c = ch0 + wv * 8 + i;
            va[i] = *(const float4*)(zb + (size_t)c * HW + hw0 + L * 4);
        }
        // fp32 loss partials (pre-rounding): tokens 4L..4L+3
#pragma unroll
        for (int i = 0; i < 8; ++i) {
            const float* p = (const float*)&va[i];
#pragma unroll
            for (int j = 0; j < 4; ++j) { zq4[j] = fmaf(p[j], p[j], zq4[j]); zs += p[j]; }
        }
#pragma unroll
        for (int i = 0; i < 8; i += 2) {
            const int cu = (wv * 8 + i) >> 1;          // channel-pair column
            const float* p0 = (const float*)&va[i];
            const float* p1 = (const float*)&va[i + 1];
#pragma unroll
            for (int j = 0; j < 4; ++j) {
                unsigned int u = ((unsigned int)f2bf(p0[j])) |
                                 ((unsigned int)f2bf(p1[j]) << 16);
                U[(L * 4 + j) * 33 + cu] = u;
            }
        }
        __syncthreads();
        // stage-out: slot -> (t4, ksl, q, tokL); consecutive tid -> consecutive
        // 16B granules of one (TB, kq) row => 1KB contiguous per wave.
#pragma unroll
        for (int r = 0; r < 4; ++r) {
            const int slot = r * 512 + tid;
            const int t4   = slot >> 9;
            const int ksl  = (slot >> 8) & 1;
            const int qq   = (slot >> 6) & 3;
            const int tokL = slot & 63;
            const int tokl = t4 * 64 + tokL;
            const int cb   = ksl * 16 + qq * 4;
            uint4 w;
            w.x = U[tokl * 33 + cb + 0];
            w.y = U[tokl * 33 + cb + 1];
            w.z = U[tokl * 33 + cb + 2];
            w.w = U[tokl * 33 + cb + 3];
            const int kq = ((ch0 >> 5) + ksl) * 4 + qq;
            *(uint4*)&zt2[(size_t)(TB0 + t4) * 16384 + kq * 512 + tokL * 8] = w;
        }
        __syncthreads();
    }

    // zsq: combine the 8 waves' channel-partials per token
#pragma unroll
    for (int j = 0; j < 4; ++j) zsqP[wv][L * 4 + j] = zq4[j];
#pragma unroll
    for (int off = 32; off > 0; off >>= 1) zs += __shfl_down(zs, off, 64);
    if (L == 0) zsums[wv] = zs;
    __syncthreads();
    if (tid < 256) {
        float s = 0.f;
#pragma unroll
        for (int w = 0; w < 8; ++w) s += zsqP[w][tid];
        zsq[(size_t)b * HW + hw0 + tid] = s;
    }
    if (tid == 0) {
        float t = 0.f;
#pragma unroll
        for (int w = 0; w < 8; ++w) t += zsums[w];
        atomicAdd(&acc_loss[1], -t);   // s_d = sum(esum[km]) - sum(z)
    }
}

// --- kernel 3: distances + argmin + loss terms. 4 waves/block, 64 tokens,
// wave w handles codes [w*256, +256). Phase 1 is a pure coalesced 32KB
// slab->LDS copy (zt2 is pre-transposed).
// (256,2) is the ONLY safe bound: every cap (128 or ~170, i.e. minwaves 3/4)
// spilled catastrophically (R1/R5/R7/R8/R9: VGPR drops, FETCH/WRITE balloon).
// kk loop is #pragma unroll'd so the scheduler software-pipelines the next
// iteration's 32 a-fragment L2 loads into the current MFMA shadow using the
// ~130 spare regs (R6 used only 124/256).
// grid 1024 x 256.
__global__ __launch_bounds__(256, 2) void vq_dist(const short* __restrict__ zt2,
                                                  const short* __restrict__ ebf2,
                                                  const float* __restrict__ esq1,
                                                  const float* __restrict__ esum,
                                                  const float* __restrict__ zsq,
                                                  unsigned short* __restrict__ inds,
                                                  float* __restrict__ acc_loss) {
    __shared__ short Zs[32 * 512];          // 32 KB, layout [kq][tokL][8ch]
    __shared__ unsigned int warr[4 * 64];

    const int tid = threadIdx.x;
    const int wid = tid >> 6;
    const int L   = tid & 63;
    const int q   = L >> 4;
    const int l15 = L & 15;
    const int TB  = blockIdx.x;
    const int tok0 = TB * 64;

    // ---- phase 1: coalesced slab copy (8 x uint4 per thread) ----
    const short* src = zt2 + (size_t)TB * 16384;
#pragma unroll
    for (int i = 0; i < 8; ++i) {
        const int g = i * 256 + tid;
        *(uint4*)&Zs[g * 8] = *(const uint4*)&src[g * 8];
    }
    __syncthreads();

    // ---- phase 2: K loop (fully unrolled over kk for cross-iter pipelining) ----
    unsigned int best[4] = {0xFFFFFFFFu, 0xFFFFFFFFu, 0xFFFFFFFFu, 0xFFFFFFFFu};

#pragma unroll
    for (int kk = 0; kk < 4; ++kk) {
        const int k0 = wid * 256 + kk * 64;
        floatx4 acc[4][4];
#pragma unroll
        for (int m = 0; m < 4; ++m)
#pragma unroll
            for (int t = 0; t < 4; ++t) acc[m][t] = (floatx4){0.f, 0.f, 0.f, 0.f};

#pragma unroll
        for (int ks = 0; ks < 8; ++ks) {
            U16 a[4];
#pragma unroll
            for (int m = 0; m < 4; ++m)
                a[m].u = *(const uint4*)(ebf2 + ((size_t)ks * K + (k0 + m * 16 + l15)) * 32 + q * 8);
            bf16x8 zf[4];
#pragma unroll
            for (int t = 0; t < 4; ++t)
                zf[t] = *(const bf16x8*)&Zs[(ks * 4 + q) * 512 + (t * 16 + l15) * 8];
#pragma unroll
            for (int m = 0; m < 4; ++m)
#pragma unroll
                for (int t = 0; t < 4; ++t)
                    acc[m][t] = __builtin_amdgcn_mfma_f32_16x16x32_bf16(a[m].b, zf[t], acc[m][t], 0, 0, 0);
        }

        // d = 1 + ||e||^2 - 2 z.e  (positive => bit-monotone); low 10 bits = code
#pragma unroll
        for (int m = 0; m < 4; ++m) {
            const float4 eq = *(const float4*)&esq1[k0 + m * 16 + q * 4];
            const float eqa[4] = {eq.x, eq.y, eq.z, eq.w};
#pragma unroll
            for (int r = 0; r < 4; ++r) {
                const unsigned int code = (unsigned int)(k0 + m * 16 + q * 4 + r);
#pragma unroll
                for (int t = 0; t < 4; ++t) {
                    float d = fmaf(-2.0f, acc[m][t][r], eqa[r]);
                    unsigned int u = (__float_as_uint(d) & 0xFFFFFC00u) | code;
                    best[t] = best[t] < u ? best[t] : u;
                }
            }
        }
    }

    // ---- phase 3: argmin reduce; epilogue computes loss terms from d_min ----
#pragma unroll
    for (int t = 0; t < 4; ++t) {
        unsigned int o = (unsigned int)__shfl_xor((int)best[t], 16, 64);
        best[t] = best[t] < o ? best[t] : o;
        o = (unsigned int)__shfl_xor((int)best[t], 32, 64);
        best[t] = best[t] < o ? best[t] : o;
    }
    warr[wid * 64 + L] = (q == 0) ? best[0] : (q == 1) ? best[1] : (q == 2) ? best[2] : best[3];
    __syncthreads();

    if (tid < 64) {
        unsigned int u0 = warr[tid];
        unsigned int u1 = warr[64 + tid];
        unsigned int u2 = warr[128 + tid];
        unsigned int u3 = warr[192 + tid];
        u0 = u0 < u1 ? u0 : u1;
        u2 = u2 < u3 ? u2 : u3;
        u0 = u0 < u2 ? u0 : u2;
        const int km = (int)(u0 & 1023u);
        inds[tok0 + tid] = (unsigned short)km;
        // ||e_km - z||^2 = (d_min - 1) + ||z||^2   (zsq is fp32, pre-rounding)
        const float d = __uint_as_float(u0 & 0xFFFFFC00u);
        float ssq = d - 1.0f + zsq[tok0 + tid];
        float sd  = esum[km];
#pragma unroll
        for (int off = 32; off > 0; off >>= 1) {
            ssq += __shfl_down(ssq, off, 64);
            sd  += __shfl_down(sd,  off, 64);
        }
        if (tid == 0) {
            atomicAdd(&acc_loss[0], ssq);
            atomicAdd(&acc_loss[1], sd);
        }
    }
}

// --- kernel 4: pure gather-write: out[b][c][hw] = emb[km(b,hw)][c].
// (straight-through forward == z_q exactly; no z traffic, no loss here).
// grid 2048 (b x ch-octet) x 256 threads; out writes are 1KB wave bursts;
// gathers are 2 x float4 per km from the L2-resident 1MB codebook.
__global__ __launch_bounds__(256) void vq_write(const float* __restrict__ emb,
                                                const unsigned short* __restrict__ inds,
                                                float* __restrict__ out) {
    const int tid = threadIdx.x;
    const int wv  = tid >> 6;
    const int L   = tid & 63;
    const int b   = blockIdx.x >> 5;
    const int c0  = (blockIdx.x & 31) * 8;
    const int hw  = wv * 256 + L * 4;

    ushort4 kmv = *(const ushort4*)(inds + b * HW + hw);
    const unsigned short kma[4] = {kmv.x, kmv.y, kmv.z, kmv.w};
    float4 elo[4], ehi[4];
#pragma unroll
    for (int j = 0; j < 4; ++j) {
        const float* er = emb + (size_t)kma[j] * C + c0;
        elo[j] = *(const float4*)er;
        ehi[j] = *(const float4*)(er + 4);
    }
    float* ob = out + ((size_t)b * C + c0) * HW + hw;
#pragma unroll
    for (int cc = 0; cc < 4; ++cc) {
        float4 v = { ((const float*)&elo[0])[cc], ((const float*)&elo[1])[cc],
                     ((const float*)&elo[2])[cc], ((const float*)&elo[3])[cc] };
        *(float4*)(ob + (size_t)cc * HW) = v;
    }
#pragma unroll
    for (int cc = 0; cc < 4; ++cc) {
        float4 v = { ((const float*)&ehi[0])[cc], ((const float*)&ehi[1])[cc],
                     ((const float*)&ehi[2])[cc], ((const float*)&ehi[3])[cc] };
        *(float4*)(ob + (size_t)(4 + cc) * HW) = v;
    }
}

// --- kernel 5: finalize scalar loss ---
__global__ void loss_kernel(const float* __restrict__ acc_loss,
                            float* __restrict__ out_loss) {
    out_loss[0] = acc_loss[0] * NTOT_INV + BETA * (acc_loss[1] * NTOT_INV);
}

extern "C" void kernel_launch(void* const* d_in, const int* in_sizes, int n_in,
                              void* d_out, int out_size, void* d_ws, size_t ws_size,
                              hipStream_t stream) {
    const float* z   = (const float*)d_in[0];   // [64,256,32,32]
    const float* emb = (const float*)d_in[1];   // [1024,256]
    float* out = (float*)d_out;                 // [16777216 z_q] + [1 loss]
    float* ws  = (float*)d_ws;
    float* acc  = ws;                               // 2 floats
    float* esq1 = ws + 64;                          // 1024 floats
    float* esum = ws + 64 + 1024;                   // 1024 floats
    short* ebf2 = (short*)(ws + 64 + 2048);         // 512 KB (tiled codebook)
    unsigned short* inds = (unsigned short*)(ebf2 + (size_t)K * C);  // 128 KB
    // Scratch in the out buffer (consumed by vq_dist before vq_write overwrites):
    short* zt2 = (short*)out;                       // 33.5 MB (slab-layout z)
    float* zsq = out + (size_t)12 * 1024 * 1024;    // 256 KB at 48MB offset

    prep_kernel<<<dim3(K / 4), 256, 0, stream>>>(emb, ebf2, esq1, esum, acc);
    zt_kernel<<<dim3(256), 512, 0, stream>>>(z, zt2, zsq, acc);
    vq_dist<<<dim3(1024), 256, 0, stream>>>(zt2, ebf2, esq1, esum, zsq, inds, acc);
    vq_write<<<dim3(2048), 256, 0, stream>>>(emb, inds, out);
    loss_kernel<<<1, 1, 0, stream>>>(acc, out + (size_t)B * C * HW);
}